// Round 5
// baseline (192.010 us; speedup 1.0000x reference)
//
#include <hip/hip_runtime.h>
#include <hip/hip_bf16.h>

// B=4, S=4096, E=256, NC=16, fp32 in/out. 4 launches:
//  pack_w:   wq/wk/wv + wo -> bf16 once; zeros the fp32 partial accumulator.
//  qkv_gemm: UNCHANGED from R4 (byte-identical).
//  flash:    NEW u=4: Q-tile 256 per block (wave owns 4 q-subtiles of 16),
//            1 block/CU (LDS 86KB, ~460 regs, launch_bounds(256,1)).
//            Rationale: LDS port was the binder at 72%/chunk; K/V LDS reads
//            are at operand-volume floor PER 32 q-rows, and Q is the
//            chunk-invariant register-held operand -> doubling q-rows/wave
//            halves LDS bytes per MFMA. MFMA floor 27.5us, LDS ~29us.
//            K dbuf 2x16K | V dbuf 2x16K | ps 20K (padded rows). One barrier
//            per chunk, one-behind PV, hoisted af reads, setprio, XCD decode
//            (K/V L2-resident), fused wo-projection epilogue in two u-passes
//            over per-wave 16KB scratch + atomicAdd into partial.
//  norm_out: out[m][o] = partial[m][o] * (1/16)/ltot[m] + bo[o]  (1MB stream)

#define S_ 4096
#define E_ 256
#define B_ 4
#define NC_ 16
#define BS_ (B_ * S_)
#define NS_ 4

typedef __attribute__((ext_vector_type(8))) short bf16x8;
typedef __attribute__((ext_vector_type(4))) float f32x4;

__device__ __forceinline__ unsigned short bf16_rtne(float f) {
    unsigned int u = __float_as_uint(f);
    return (unsigned short)((u + 0x7FFFu + ((u >> 16) & 1u)) >> 16);
}
__device__ __forceinline__ bf16x8 pack8(f32x4 a, f32x4 b) {
    bf16x8 r;
#pragma unroll
    for (int i = 0; i < 4; i++) r[i] = (short)bf16_rtne(a[i]);
#pragma unroll
    for (int i = 0; i < 4; i++) r[4 + i] = (short)bf16_rtne(b[i]);
    return r;
}
__device__ __forceinline__ void gl_lds16(const void* g, void* lds) {
    __builtin_amdgcn_global_load_lds(
        (const __attribute__((address_space(1))) unsigned int*)g,
        (__attribute__((address_space(3))) unsigned int*)lds, 16, 0, 0);
}
// XOR swizzle on 16B LDS units: involution (mask from bits >=3 flips bits 0-2).
__device__ __forceinline__ int swz_u(int q) { return q ^ ((q >> 3) & 7); }

// ---------------------------------------------------------------------------
// pack_w: wq/wk/wv [E,E] fp32 -> wb bf16 (3 slabs); wo [NC,E] -> wbo;
// zero partial[BS,NC] f32. Grid 226 x 256, units of 8 elems.
// ---------------------------------------------------------------------------
#define WUNITS_ (3 * E_ * E_ / 8)   // 24576
#define WOUNITS_ (NC_ * E_ / 8)     // 512
#define ZUNITS_ (BS_ * NC_ / 8)     // 32768
__global__ __launch_bounds__(256) void pack_w(
    const float* __restrict__ wq, const float* __restrict__ wk,
    const float* __restrict__ wv, const float* __restrict__ wo,
    short* __restrict__ wb, short* __restrict__ wbo,
    float* __restrict__ partial) {
    int u = blockIdx.x * 256 + threadIdx.x;
    const float* src;
    short* dst;
    if (u < WUNITS_) {
        int sel = u >> 13;  // 8192 units per weight matrix
        int off = (u & 8191) * 8;
        src = ((sel == 0) ? wq : (sel == 1) ? wk : wv) + off;
        dst = wb + sel * (E_ * E_) + off;
    } else if (u < WUNITS_ + WOUNITS_) {
        int u2 = u - WUNITS_;
        src = wo + (size_t)u2 * 8;
        dst = wbo + (size_t)u2 * 8;
    } else {
        int zu = u - (WUNITS_ + WOUNITS_);  // < ZUNITS_
        f32x4 z = {0.f, 0.f, 0.f, 0.f};
        ((f32x4*)partial)[zu * 2] = z;
        ((f32x4*)partial)[zu * 2 + 1] = z;
        return;
    }
    f32x4 a = *(const f32x4*)src;
    f32x4 b = *(const f32x4*)(src + 4);
    *(bf16x8*)dst = pack8(a, b);
}

// ---------------------------------------------------------------------------
// qkv_gemm. UNCHANGED from R4. 1-D grid 768, XCD decode.
// ---------------------------------------------------------------------------
__global__ __launch_bounds__(256) void qkv_gemm(
    const float* __restrict__ x, const short* __restrict__ wb,
    const float* __restrict__ bq, const float* __restrict__ bk,
    const float* __restrict__ bv, short* __restrict__ Qb,
    short* __restrict__ Kb, short* __restrict__ Vtc) {
    __shared__ __align__(16) short stg[2][8192]; // 2 x 16KB: wt 1024 units
    __shared__ __align__(16) short epi[16896];   // 64x264 (Q/K) or 2x8192 (V)

    int t = threadIdx.x;
    int lin = blockIdx.x;
    int xcd = lin & 7, r8 = lin >> 3;
    int sel = r8 >> 5;
    int m0 = (((xcd << 5) | (r8 & 31))) * 64;
    int lane = t & 63, wid = t >> 6, quad = lane >> 4, idx = lane & 15;

    const short* wsel = wb + sel * (E_ * E_);
    const float* bias = (sel == 0) ? bq : (sel == 1) ? bk : bv;

    const short* wsrc[4];
#pragma unroll
    for (int i = 0; i < 4; i++) {
        int q = i * 256 + t, u = swz_u(q);
        wsrc[i] = wsel + (size_t)(u >> 2) * E_ + (u & 3) * 8;
    }

    // prologue: stage w kc=0 into buf 0 (DMA latency hides under x pack)
#pragma unroll
    for (int i = 0; i < 4; i++) gl_lds16(wsrc[i], &stg[0][(i * 256 + t) * 8]);

    // x rows -> registers: row m0+wid*16+idx, cols quad*8 + it*32 .. +7
    const float* xrow = x + (size_t)(m0 + wid * 16 + idx) * E_ + quad * 8;
    bf16x8 af[8];
#pragma unroll
    for (int it = 0; it < 8; it++) {
        f32x4 a0 = *(const f32x4*)(xrow + it * 32);
        f32x4 a1 = *(const f32x4*)(xrow + it * 32 + 4);
        af[it] = pack8(a0, a1);
    }

    f32x4 zf = {0.f, 0.f, 0.f, 0.f};
    f32x4 acc[16];
#pragma unroll
    for (int i = 0; i < 16; i++) acc[i] = zf;

    int fo = (idx * 4 + quad) ^ (idx >> 1); // swizzled fragment unit offset

#pragma unroll
    for (int it = 0; it < 8; it++) {
        __syncthreads(); // drains DMAs staged one full K-step ago
        if (it < 7) {
            int kc = (it + 1) * 32;
            short* d = stg[(it + 1) & 1];
#pragma unroll
            for (int i = 0; i < 4; i++)
                gl_lds16(wsrc[i] + kc, &d[(i * 256 + t) * 8]);
        }
        const short* cw = &stg[it & 1][fo * 8];
        __builtin_amdgcn_s_setprio(1);
#pragma unroll
        for (int ct = 0; ct < 16; ct++)
            acc[ct] = __builtin_amdgcn_mfma_f32_16x16x32_bf16(
                af[it], *(const bf16x8*)&cw[ct * 512], acc[ct], 0, 0, 0);
        __builtin_amdgcn_s_setprio(0);
    }

    int qr = quad * 4;
    if (sel == 2) {
        // V: chunk slab, position = key-interleave permutation + 16B swizzle
#pragma unroll
        for (int ct = 0; ct < 16; ct++) {
            int e = ct * 16 + idx;
            float bb = bias[e];
#pragma unroll
            for (int r = 0; r < 4; r++) {
                int mr = wid * 16 + qr + r; // 0..63
                int ckg = mr >> 5, sin = mr & 31;
                int sp = ((sin & 15) << 1) | (sin >> 4); // interleaved position
                int pos = (sp >> 3) ^ ((e >> 1) & 3);
                epi[ckg * 8192 + e * 32 + pos * 8 + (sp & 7)] =
                    (short)bf16_rtne(acc[ct][r] + bb);
            }
        }
        __syncthreads();
        size_t base = ((size_t)((m0 >> 12) * 128 + ((m0 & (S_ - 1)) >> 5))) * 8192;
#pragma unroll
        for (int j = 0; j < 8; j++) {
            int unit = j * 256 + t;
            *(bf16x8*)(Vtc + base + (size_t)unit * 8) = *(const bf16x8*)&epi[unit * 8];
        }
    } else {
        float alpha = (sel == 0) ? 0.0625f : 1.0f;
#pragma unroll
        for (int ct = 0; ct < 16; ct++) {
            int n = ct * 16 + idx;
            float bb = bias[n];
#pragma unroll
            for (int r = 0; r < 4; r++) {
                int row = wid * 16 + qr + r;
                int col = (sel == 1) ? ((((n >> 3) ^ (row & 7)) << 3) | (n & 7)) : n;
                epi[row * 264 + col] = (short)bf16_rtne((acc[ct][r] + bb) * alpha);
            }
        }
        __syncthreads();
        short* out = (sel == 0) ? Qb : Kb;
#pragma unroll
        for (int j = 0; j < 8; j++) {
            int g = j * 256 + t;
            int row = g >> 5, seg = g & 31;
            *(bf16x8*)(out + (size_t)(m0 + row) * E_ + seg * 8) =
                *(const bf16x8*)&epi[row * 264 + seg * 8];
        }
    }
}

// ---------------------------------------------------------------------------
// Flash + fused out-projection, u=4. 1-D grid 256, XCD decode (2 pairs/XCD,
// K/V L2-resident). LDS 86016 B: K dbuf 2x16K | V dbuf 2x16K | ps 4x5K.
// 1 block/CU, 1 wave/SIMD, ~460 regs (launch_bounds(256,1): no spill < 512).
// ---------------------------------------------------------------------------
__global__ __launch_bounds__(256, 1) void flash_attn(
    const short* __restrict__ Qb, const short* __restrict__ Kb,
    const short* __restrict__ Vtc, const short* __restrict__ wbo,
    float* __restrict__ partial, float* __restrict__ lpart) {
    __shared__ __align__(16) short lds[43008]; // 86016 B
    // kb(par) = lds + par*8192 ; vb(par) = lds + 16384 + par*8192 ; ps at 32768

    int t = threadIdx.x;
    int lin = blockIdx.x;                       // 0..255
    int xcd = lin & 7, r5 = lin >> 3;           // r5 0..31
    int pair = (xcd << 1) | (r5 >> 4);          // 0..15
    int b = pair >> 2, slice = pair & 3, q0 = (r5 & 15) * 256;
    int key0 = slice * (S_ / NS_);
    const int nchunk = (S_ / NS_) / 32; // 32
    int lane = t & 63, wv = t >> 6, quad = lane >> 4, idx = lane & 15;

    bf16x8 qf[4][8];
#pragma unroll
    for (int u = 0; u < 4; u++) {
        const short* qrow = Qb + (size_t)(b * S_ + q0 + u * 64 + wv * 16 + idx) * E_ + quad * 8;
#pragma unroll
        for (int c = 0; c < 8; c++) qf[u][c] = *(const bf16x8*)(qrow + c * 32);
    }

    f32x4 zf = {0.f, 0.f, 0.f, 0.f};
    f32x4 oacc[4][16];
#pragma unroll
    for (int u = 0; u < 4; u++)
#pragma unroll
        for (int i = 0; i < 16; i++) oacc[u][i] = zf;
    float ls[4][4] = {{0, 0, 0, 0}, {0, 0, 0, 0}, {0, 0, 0, 0}, {0, 0, 0, 0}};

    const short* kg = Kb + (size_t)(b * S_ + key0) * E_ + lane * 8;
    const short* vg = Vtc + ((size_t)(b * 128 + (key0 >> 5))) * 8192 + lane * 8;
    short* psw = lds + 32768 + wv * 2560; // per-wave 2560 shorts (4u x 16r x 20dw)
    unsigned int* pswu = (unsigned int*)psw;
    int vsw = (quad ^ ((idx >> 1) & 3)) << 3;

    // prologue: stage K(0), V(0), K(1)
#pragma unroll
    for (int j = 0; j < 4; j++) gl_lds16(kg + (wv * 4 + j) * 512, &lds[(wv * 4 + j) * 512]);
#pragma unroll
    for (int j = 0; j < 4; j++) gl_lds16(vg + (wv * 4 + j) * 512, &lds[16384 + (wv * 4 + j) * 512]);
#pragma unroll
    for (int j = 0; j < 4; j++) gl_lds16(kg + 8192 + (wv * 4 + j) * 512, &lds[8192 + (wv * 4 + j) * 512]);
    __syncthreads();

    // QK(0) + exp(0)
    {
        f32x4 s[8] = {zf, zf, zf, zf, zf, zf, zf, zf};
        __builtin_amdgcn_s_setprio(1);
#pragma unroll
        for (int c = 0; c < 8; c++) {
            int p = (((c * 4 + quad) ^ (idx & 7)) << 3);
            bf16x8 k0 = *(const bf16x8*)&lds[idx * 256 + p];
            bf16x8 k1 = *(const bf16x8*)&lds[(16 + idx) * 256 + p];
#pragma unroll
            for (int u = 0; u < 4; u++) {
                s[u * 2] = __builtin_amdgcn_mfma_f32_16x16x32_bf16(qf[u][c], k0, s[u * 2], 0, 0, 0);
                s[u * 2 + 1] = __builtin_amdgcn_mfma_f32_16x16x32_bf16(qf[u][c], k1, s[u * 2 + 1], 0, 0, 0);
            }
        }
        __builtin_amdgcn_s_setprio(0);
#pragma unroll
        for (int u = 0; u < 4; u++)
#pragma unroll
            for (int r = 0; r < 4; r++) {
                float p0 = __expf(s[u * 2][r]);
                float p1 = __expf(s[u * 2 + 1][r]);
                ls[u][r] += p0 + p1;
                pswu[u * 320 + (quad * 4 + r) * 20 + idx] =
                    (unsigned int)bf16_rtne(p0) | ((unsigned int)bf16_rtne(p1) << 16);
            }
    }

    for (int ck = 0; ck < nchunk - 1; ck++) {
        __syncthreads(); // drains K(ck+1), V(ck) DMAs (staged one full chunk ago)
        // ---- af(ck) read hoisted: full chunk of ds flight before PV needs it.
        bf16x8 af[4];
#pragma unroll
        for (int u = 0; u < 4; u++)
            af[u] = *(const bf16x8*)&psw[u * 640 + idx * 40 + quad * 8];
        if (ck + 2 < nchunk) {
            const short* ks = kg + (size_t)(ck + 2) * 8192;
            short* kd = lds + (ck & 1) * 8192;
#pragma unroll
            for (int j = 0; j < 4; j++) gl_lds16(ks + (wv * 4 + j) * 512, &kd[(wv * 4 + j) * 512]);
        }
        {
            const short* vs = vg + (size_t)(ck + 1) * 8192;
            short* vd = lds + 16384 + ((ck + 1) & 1) * 8192;
#pragma unroll
            for (int j = 0; j < 4; j++) gl_lds16(vs + (wv * 4 + j) * 512, &vd[(wv * 4 + j) * 512]);
        }
        // ---- QK(ck+1) ----
        const short* kc = lds + ((ck + 1) & 1) * 8192;
        f32x4 s[8] = {zf, zf, zf, zf, zf, zf, zf, zf};
        __builtin_amdgcn_s_setprio(1);
#pragma unroll
        for (int c = 0; c < 8; c++) {
            int p = (((c * 4 + quad) ^ (idx & 7)) << 3);
            bf16x8 k0 = *(const bf16x8*)&kc[idx * 256 + p];
            bf16x8 k1 = *(const bf16x8*)&kc[(16 + idx) * 256 + p];
#pragma unroll
            for (int u = 0; u < 4; u++) {
                s[u * 2] = __builtin_amdgcn_mfma_f32_16x16x32_bf16(qf[u][c], k0, s[u * 2], 0, 0, 0);
                s[u * 2 + 1] = __builtin_amdgcn_mfma_f32_16x16x32_bf16(qf[u][c], k1, s[u * 2 + 1], 0, 0, 0);
            }
        }
        __builtin_amdgcn_s_setprio(0);
        // ---- exp(ck+1) -> ps (independent of PV(ck); hides under it) ----
#pragma unroll
        for (int u = 0; u < 4; u++)
#pragma unroll
            for (int r = 0; r < 4; r++) {
                float p0 = __expf(s[u * 2][r]);
                float p1 = __expf(s[u * 2 + 1][r]);
                ls[u][r] += p0 + p1;
                pswu[u * 320 + (quad * 4 + r) * 20 + idx] =
                    (unsigned int)bf16_rtne(p0) | ((unsigned int)bf16_rtne(p1) << 16);
            }
        // ---- PV(ck) ----
        const short* vc = lds + 16384 + (ck & 1) * 8192;
        __builtin_amdgcn_s_setprio(1);
#pragma unroll
        for (int ct = 0; ct < 16; ct++) {
            bf16x8 v = *(const bf16x8*)&vc[(ct * 16 + idx) * 32 + vsw];
#pragma unroll
            for (int u = 0; u < 4; u++)
                oacc[u][ct] = __builtin_amdgcn_mfma_f32_16x16x32_bf16(af[u], v, oacc[u][ct], 0, 0, 0);
        }
        __builtin_amdgcn_s_setprio(0);
    }
    __syncthreads(); // drain V(nchunk-1)
    {
        bf16x8 af[4];
#pragma unroll
        for (int u = 0; u < 4; u++)
            af[u] = *(const bf16x8*)&psw[u * 640 + idx * 40 + quad * 8];
        const short* vc = lds + 16384 + ((nchunk - 1) & 1) * 8192;
        __builtin_amdgcn_s_setprio(1);
#pragma unroll
        for (int ct = 0; ct < 16; ct++) {
            bf16x8 v = *(const bf16x8*)&vc[(ct * 16 + idx) * 32 + vsw];
#pragma unroll
            for (int u = 0; u < 4; u++)
                oacc[u][ct] = __builtin_amdgcn_mfma_f32_16x16x32_bf16(af[u], v, oacc[u][ct], 0, 0, 0);
        }
        __builtin_amdgcn_s_setprio(0);
    }
    __syncthreads(); // all compute reads of kb/vb done; reuse as epilogue scratch

    // ---- row sums ----
#pragma unroll
    for (int u = 0; u < 4; u++)
#pragma unroll
        for (int r = 0; r < 4; r++) {
            float v = ls[u][r];
            v += __shfl_xor(v, 1);
            v += __shfl_xor(v, 2);
            v += __shfl_xor(v, 4);
            v += __shfl_xor(v, 8);
            if (idx == 0)
                lpart[(size_t)slice * BS_ + b * S_ + q0 + u * 64 + wv * 16 + quad * 4 + r] = v;
        }

    // ---- Epilogue in two u-passes over per-wave 16 KB scratch (overlays
    // kb/vb; per-wave private, DS in-order -> no barrier between passes).
    short* scr = lds + wv * 8192;
#pragma unroll
    for (int up = 0; up < 2; up++) {
#pragma unroll
        for (int uu = 0; uu < 2; uu++) {
            int u = up * 2 + uu;
#pragma unroll
            for (int ct = 0; ct < 16; ct++) {
                int e = ct * 16 + idx;
#pragma unroll
                for (int r = 0; r < 4; r++) {
                    int lr = quad * 4 + r;
                    scr[uu * 4096 + lr * 256 + ((((e >> 3) ^ (lr & 7)) << 3) | (e & 7))] =
                        (short)bf16_rtne(oacc[u][ct][r]);
                }
            }
        }
        // fused out-projection: 32q x 256E (bf16) x woT -> 32q x 16o fp32
        f32x4 pacc[2] = {zf, zf};
#pragma unroll
        for (int c = 0; c < 8; c++) {
            bf16x8 bw = *(const bf16x8*)(wbo + idx * E_ + c * 32 + quad * 8);
#pragma unroll
            for (int uu = 0; uu < 2; uu++) {
                bf16x8 pa = *(const bf16x8*)&scr[uu * 4096 + idx * 256 +
                                                 (((c * 4 + quad) ^ (idx & 7)) << 3)];
                pacc[uu] = __builtin_amdgcn_mfma_f32_16x16x32_bf16(pa, bw, pacc[uu], 0, 0, 0);
            }
        }
#pragma unroll
        for (int uu = 0; uu < 2; uu++)
#pragma unroll
            for (int r = 0; r < 4; r++) {
                int m = q0 + (up * 2 + uu) * 64 + wv * 16 + quad * 4 + r;
                atomicAdd(&partial[((size_t)b * S_ + m) * NC_ + idx], pacc[uu][r]);
            }
    }
}

// ---------------------------------------------------------------------------
// norm_out: out[m][o] = partial[m][o] * (1/16)/ltot[m] + bo[o]. Grid 1024x256.
// ---------------------------------------------------------------------------
__global__ __launch_bounds__(256) void norm_out(
    const float* __restrict__ partial, const float* __restrict__ lpart,
    const float* __restrict__ bo, float* __restrict__ out) {
    int t = threadIdx.x;
    int m = blockIdx.x * 16 + (t >> 4), o = t & 15;
    float ltot = 0.f;
#pragma unroll
    for (int ns = 0; ns < NS_; ns++) ltot += lpart[(size_t)ns * BS_ + m];
    size_t i = (size_t)m * NC_ + o;
    out[i] = partial[i] * (0.0625f / ltot) + bo[o];
}

extern "C" void kernel_launch(void* const* d_in, const int* in_sizes, int n_in,
                              void* d_out, int out_size, void* d_ws, size_t ws_size,
                              hipStream_t stream) {
    const float* x  = (const float*)d_in[0];
    const float* wq = (const float*)d_in[1];
    const float* bq = (const float*)d_in[2];
    const float* wk = (const float*)d_in[3];
    const float* bk = (const float*)d_in[4];
    const float* wv = (const float*)d_in[5];
    const float* bv = (const float*)d_in[6];
    const float* wo = (const float*)d_in[7];
    const float* bo = (const float*)d_in[8];
    float* out = (float*)d_out;

    const size_t NEL = (size_t)BS_ * E_; // 4,194,304
    // ws (shorts): Qb | Kb | Vtc | wb(3*E*E) | wbo(NC*E) | partial f32 | lpart f32
    short* Qb = (short*)d_ws;
    short* Kb = Qb + NEL;
    short* Vtc = Kb + NEL;
    short* wb = Vtc + NEL;
    short* wbo = wb + (size_t)3 * E_ * E_;
    float* partial = (float*)(wbo + (size_t)NC_ * E_);   // BS_*NC_ f32 = 1 MB
    float* lpart = partial + (size_t)BS_ * NC_;          // NS_*BS_ f32 = 256 KB

    pack_w<<<(WUNITS_ + WOUNITS_ + ZUNITS_) / 256, 256, 0, stream>>>(
        wq, wk, wv, wo, wb, wbo, partial);
    qkv_gemm<<<dim3(768), 256, 0, stream>>>(x, wb, bq, bk, bv, Qb, Kb, Vtc);
    flash_attn<<<dim3(256), 256, 0, stream>>>(Qb, Kb, Vtc, wbo, partial, lpart);
    norm_out<<<dim3(BS_ / 16), 256, 0, stream>>>(partial, lpart, bo, out);
}

// Round 6
// 172.609 us; speedup vs baseline: 1.1124x; 1.1124x over previous
//
#include <hip/hip_runtime.h>
#include <hip/hip_bf16.h>

// B=4, S=4096, E=256, NC=16, fp32 in/out. 3 launches:
//  qkv_gemm: A (x rows) fp32->reg->bf16 in prologue; B (w) staged fp32->reg
//            (issue-early, T14) -> pack8 -> ds_write_b128 (write-late) into
//            XOR-swizzled dbuf, ONE barrier per K-step. Also zeroes the fp32
//            partial accumulator (stream-precedes flash). XCD-aware decode.
//            pack_w kernel deleted (no wb/wbo intermediates).
//  flash:    EXACT R4 81-us structure (u=2, 2 blocks/CU, K/V dbuf + padded ps,
//            one barrier/chunk, one-behind PV, hoisted af reads, setprio, XCD
//            decode -> K/V L2-resident, fused wo-projection epilogue with
//            atomicAdd). Only change: bw fragments packed inline from fp32 wo
//            (bit-identical rtne) instead of reading a pre-packed wbo.
//  norm_out: out[m][o] = partial[m][o] * (1/16)/ltot[m] + bo[o]  (1MB stream)
//
// R5 lesson encoded here: u=4 (256+ regs) forces 1 wave/SIMD -> latency
// exposure, 102us. u=2 at 2 waves/SIMD is the reg-feasible optimum of this
// structure; occupancy >2 needs <=128 regs/wave (u=1 redesign, not this round).

#define S_ 4096
#define E_ 256
#define B_ 4
#define NC_ 16
#define BS_ (B_ * S_)
#define NS_ 4

typedef __attribute__((ext_vector_type(8))) short bf16x8;
typedef __attribute__((ext_vector_type(4))) float f32x4;

__device__ __forceinline__ unsigned short bf16_rtne(float f) {
    unsigned int u = __float_as_uint(f);
    return (unsigned short)((u + 0x7FFFu + ((u >> 16) & 1u)) >> 16);
}
__device__ __forceinline__ bf16x8 pack8(f32x4 a, f32x4 b) {
    bf16x8 r;
#pragma unroll
    for (int i = 0; i < 4; i++) r[i] = (short)bf16_rtne(a[i]);
#pragma unroll
    for (int i = 0; i < 4; i++) r[4 + i] = (short)bf16_rtne(b[i]);
    return r;
}
__device__ __forceinline__ void gl_lds16(const void* g, void* lds) {
    __builtin_amdgcn_global_load_lds(
        (const __attribute__((address_space(1))) unsigned int*)g,
        (__attribute__((address_space(3))) unsigned int*)lds, 16, 0, 0);
}
// XOR swizzle on 16B LDS units: involution (mask from bits >=3 flips bits 0-2).
__device__ __forceinline__ int swz_u(int q) { return q ^ ((q >> 3) & 7); }

// ---------------------------------------------------------------------------
// qkv_gemm. 1-D grid 768. 256 thr = 4 waves; wave: 16 rows x 256 cols.
// XCD decode: xcd = bid&7; same m0's 3 sels co-located per XCD (x L2 hits).
// A: fp32 x rows -> registers (8 bf16x8/thread), bit-identical rtne pack.
// B: w fp32 -> regs (issued before MFMA cluster) -> pack -> ds_write into
// swizzled dbuf after MFMAs; one barrier per K-step (end of body).
// Also zeroes partial[BS,NC] (2 f32/thread, guarded).
// ---------------------------------------------------------------------------
__global__ __launch_bounds__(256) void qkv_gemm(
    const float* __restrict__ x, const float* __restrict__ wq,
    const float* __restrict__ wk, const float* __restrict__ wv,
    const float* __restrict__ bq, const float* __restrict__ bk,
    const float* __restrict__ bv, short* __restrict__ Qb,
    short* __restrict__ Kb, short* __restrict__ Vtc,
    float* __restrict__ partial) {
    __shared__ __align__(16) short stg[2][8192]; // 2 x 16KB: wt 1024 units
    __shared__ __align__(16) short epi[16896];   // 64x264 (Q/K) or 2x8192 (V)

    int t = threadIdx.x;
    int lin = blockIdx.x;
    int xcd = lin & 7, r8 = lin >> 3;
    int sel = r8 >> 5;
    int m0 = (((xcd << 5) | (r8 & 31))) * 64;
    int lane = t & 63, wid = t >> 6, quad = lane >> 4, idx = lane & 15;

    const float* wsel = (sel == 0) ? wq : (sel == 1) ? wk : wv;
    const float* bias = (sel == 0) ? bq : (sel == 1) ? bk : bv;

    // w fp32 sources: physical LDS unit q holds logical unit swz_u(q)
    const float* wsrc[4];
#pragma unroll
    for (int i = 0; i < 4; i++) {
        int q = i * 256 + t, u = swz_u(q);
        wsrc[i] = wsel + (size_t)(u >> 2) * E_ + (u & 3) * 8;
    }

    // prologue: w step0 -> regs (flight covers the x pack below)
    f32x4 wf[8];
#pragma unroll
    for (int i = 0; i < 4; i++) {
        wf[i * 2] = *(const f32x4*)(wsrc[i]);
        wf[i * 2 + 1] = *(const f32x4*)(wsrc[i] + 4);
    }

    // zero partial: 262144 f32 over 196608 threads (2 each, guarded)
    {
        int z = lin * 256 + t;
        partial[z] = 0.f;
        if (z < BS_ * NC_ - 196608) partial[z + 196608] = 0.f;
    }

    // x rows -> registers: row m0+wid*16+idx, cols quad*8 + it*32 .. +7
    const float* xrow = x + (size_t)(m0 + wid * 16 + idx) * E_ + quad * 8;
    bf16x8 af[8];
#pragma unroll
    for (int it = 0; it < 8; it++) {
        f32x4 a0 = *(const f32x4*)(xrow + it * 32);
        f32x4 a1 = *(const f32x4*)(xrow + it * 32 + 4);
        af[it] = pack8(a0, a1);
    }

    // write w step0 into buf 0
#pragma unroll
    for (int i = 0; i < 4; i++)
        *(bf16x8*)&stg[0][(i * 256 + t) * 8] = pack8(wf[i * 2], wf[i * 2 + 1]);

    f32x4 zf = {0.f, 0.f, 0.f, 0.f};
    f32x4 acc[16];
#pragma unroll
    for (int i = 0; i < 16; i++) acc[i] = zf;

    int fo = (idx * 4 + quad) ^ (idx >> 1); // swizzled fragment unit offset

    __syncthreads(); // buf 0 visible to all waves

#pragma unroll
    for (int it = 0; it < 8; it++) {
        // issue-early: w loads for step it+1 (hide under MFMA cluster)
        if (it < 7) {
            int kc = (it + 1) * 32;
#pragma unroll
            for (int i = 0; i < 4; i++) {
                wf[i * 2] = *(const f32x4*)(wsrc[i] + kc);
                wf[i * 2 + 1] = *(const f32x4*)(wsrc[i] + kc + 4);
            }
        }
        const short* cw = &stg[it & 1][fo * 8];
        __builtin_amdgcn_s_setprio(1);
#pragma unroll
        for (int ct = 0; ct < 16; ct++)
            acc[ct] = __builtin_amdgcn_mfma_f32_16x16x32_bf16(
                af[it], *(const bf16x8*)&cw[ct * 512], acc[ct], 0, 0, 0);
        __builtin_amdgcn_s_setprio(0);
        // write-late: pack + ds_write into the buffer all waves finished
        // reading before the PREVIOUS barrier (dbuf-safe).
        if (it < 7) {
            short* d = stg[(it + 1) & 1];
#pragma unroll
            for (int i = 0; i < 4; i++)
                *(bf16x8*)&d[(i * 256 + t) * 8] = pack8(wf[i * 2], wf[i * 2 + 1]);
        }
        __syncthreads();
    }

    int qr = quad * 4;
    if (sel == 2) {
        // V: chunk slab, position = key-interleave permutation + 16B swizzle
#pragma unroll
        for (int ct = 0; ct < 16; ct++) {
            int e = ct * 16 + idx;
            float bb = bias[e];
#pragma unroll
            for (int r = 0; r < 4; r++) {
                int mr = wid * 16 + qr + r; // 0..63
                int ckg = mr >> 5, sin = mr & 31;
                int sp = ((sin & 15) << 1) | (sin >> 4); // interleaved position
                int pos = (sp >> 3) ^ ((e >> 1) & 3);
                epi[ckg * 8192 + e * 32 + pos * 8 + (sp & 7)] =
                    (short)bf16_rtne(acc[ct][r] + bb);
            }
        }
        __syncthreads();
        size_t base = ((size_t)((m0 >> 12) * 128 + ((m0 & (S_ - 1)) >> 5))) * 8192;
#pragma unroll
        for (int j = 0; j < 8; j++) {
            int unit = j * 256 + t;
            *(bf16x8*)(Vtc + base + (size_t)unit * 8) = *(const bf16x8*)&epi[unit * 8];
        }
    } else {
        float alpha = (sel == 0) ? 0.0625f : 1.0f;
#pragma unroll
        for (int ct = 0; ct < 16; ct++) {
            int n = ct * 16 + idx;
            float bb = bias[n];
#pragma unroll
            for (int r = 0; r < 4; r++) {
                int row = wid * 16 + qr + r;
                int col = (sel == 1) ? ((((n >> 3) ^ (row & 7)) << 3) | (n & 7)) : n;
                epi[row * 264 + col] = (short)bf16_rtne((acc[ct][r] + bb) * alpha);
            }
        }
        __syncthreads();
        short* out = (sel == 0) ? Qb : Kb;
#pragma unroll
        for (int j = 0; j < 8; j++) {
            int g = j * 256 + t;
            int row = g >> 5, seg = g & 31;
            *(bf16x8*)(out + (size_t)(m0 + row) * E_ + seg * 8) =
                *(const bf16x8*)&epi[row * 264 + seg * 8];
        }
    }
}

// ---------------------------------------------------------------------------
// Flash + fused out-projection. EXACT R4 81-us structure (u=2, 2 blocks/CU).
// Only change: bw packed inline from fp32 wo (bit-identical rtne).
// 1-D grid 512, XCD decode (K/V L2-resident). LDS 74 KB.
// ---------------------------------------------------------------------------
__global__ __launch_bounds__(256, 2) void flash_attn(
    const short* __restrict__ Qb, const short* __restrict__ Kb,
    const short* __restrict__ Vtc, const float* __restrict__ wo,
    float* __restrict__ partial, float* __restrict__ lpart) {
    __shared__ __align__(16) short lds[37888]; // 75776 B
    // kb(par) = lds + par*8192 ; vb(par) = lds + 16384 + par*8192 ; ps at 32768

    int t = threadIdx.x;
    int lin = blockIdx.x;                       // 0..511
    int xcd = lin & 7, r8 = lin >> 3;           // r8 0..63
    int pair = (xcd << 1) | (r8 >> 5);          // 0..15
    int b = pair >> 2, slice = pair & 3, q0 = (r8 & 31) * 128;
    int key0 = slice * (S_ / NS_);
    const int nchunk = (S_ / NS_) / 32; // 32
    int lane = t & 63, wv = t >> 6, quad = lane >> 4, idx = lane & 15;

    bf16x8 qf[2][8];
#pragma unroll
    for (int u = 0; u < 2; u++) {
        const short* qrow = Qb + (size_t)(b * S_ + q0 + u * 64 + wv * 16 + idx) * E_ + quad * 8;
#pragma unroll
        for (int c = 0; c < 8; c++) qf[u][c] = *(const bf16x8*)(qrow + c * 32);
    }

    f32x4 zf = {0.f, 0.f, 0.f, 0.f};
    f32x4 oacc[2][16];
#pragma unroll
    for (int u = 0; u < 2; u++)
#pragma unroll
        for (int i = 0; i < 16; i++) oacc[u][i] = zf;
    float ls[2][4] = {{0, 0, 0, 0}, {0, 0, 0, 0}};

    const short* kg = Kb + (size_t)(b * S_ + key0) * E_ + lane * 8;
    const short* vg = Vtc + ((size_t)(b * 128 + (key0 >> 5))) * 8192 + lane * 8;
    short* psw = lds + 32768 + wv * 1280; // per-wave 1280 shorts (2u x 16r x 20dw)
    unsigned int* pswu = (unsigned int*)psw;
    int vsw = (quad ^ ((idx >> 1) & 3)) << 3;

    // prologue: stage K(0), V(0), K(1)
#pragma unroll
    for (int j = 0; j < 4; j++) gl_lds16(kg + (wv * 4 + j) * 512, &lds[(wv * 4 + j) * 512]);
#pragma unroll
    for (int j = 0; j < 4; j++) gl_lds16(vg + (wv * 4 + j) * 512, &lds[16384 + (wv * 4 + j) * 512]);
#pragma unroll
    for (int j = 0; j < 4; j++) gl_lds16(kg + 8192 + (wv * 4 + j) * 512, &lds[8192 + (wv * 4 + j) * 512]);
    __syncthreads();

    // QK(0) + exp(0)
    {
        f32x4 s[4] = {zf, zf, zf, zf};
        __builtin_amdgcn_s_setprio(1);
#pragma unroll
        for (int c = 0; c < 8; c++) {
            int p = (((c * 4 + quad) ^ (idx & 7)) << 3);
            bf16x8 k0 = *(const bf16x8*)&lds[idx * 256 + p];
            bf16x8 k1 = *(const bf16x8*)&lds[(16 + idx) * 256 + p];
            s[0] = __builtin_amdgcn_mfma_f32_16x16x32_bf16(qf[0][c], k0, s[0], 0, 0, 0);
            s[1] = __builtin_amdgcn_mfma_f32_16x16x32_bf16(qf[0][c], k1, s[1], 0, 0, 0);
            s[2] = __builtin_amdgcn_mfma_f32_16x16x32_bf16(qf[1][c], k0, s[2], 0, 0, 0);
            s[3] = __builtin_amdgcn_mfma_f32_16x16x32_bf16(qf[1][c], k1, s[3], 0, 0, 0);
        }
        __builtin_amdgcn_s_setprio(0);
#pragma unroll
        for (int u = 0; u < 2; u++)
#pragma unroll
            for (int r = 0; r < 4; r++) {
                float p0 = __expf(s[u * 2][r]);
                float p1 = __expf(s[u * 2 + 1][r]);
                ls[u][r] += p0 + p1;
                pswu[u * 320 + (quad * 4 + r) * 20 + idx] =
                    (unsigned int)bf16_rtne(p0) | ((unsigned int)bf16_rtne(p1) << 16);
            }
    }

    for (int ck = 0; ck < nchunk - 1; ck++) {
        __syncthreads(); // drains K(ck+1), V(ck) DMAs (staged one full chunk ago)
        // ---- af(ck) read hoisted: full chunk of ds flight before PV needs it.
        bf16x8 af0 = *(const bf16x8*)&psw[idx * 40 + quad * 8];
        bf16x8 af1 = *(const bf16x8*)&psw[640 + idx * 40 + quad * 8];
        if (ck + 2 < nchunk) {
            const short* ks = kg + (size_t)(ck + 2) * 8192;
            short* kd = lds + (ck & 1) * 8192;
#pragma unroll
            for (int j = 0; j < 4; j++) gl_lds16(ks + (wv * 4 + j) * 512, &kd[(wv * 4 + j) * 512]);
        }
        {
            const short* vs = vg + (size_t)(ck + 1) * 8192;
            short* vd = lds + 16384 + ((ck + 1) & 1) * 8192;
#pragma unroll
            for (int j = 0; j < 4; j++) gl_lds16(vs + (wv * 4 + j) * 512, &vd[(wv * 4 + j) * 512]);
        }
        // ---- QK(ck+1) ----
        const short* kc = lds + ((ck + 1) & 1) * 8192;
        f32x4 s[4] = {zf, zf, zf, zf};
        __builtin_amdgcn_s_setprio(1);
#pragma unroll
        for (int c = 0; c < 8; c++) {
            int p = (((c * 4 + quad) ^ (idx & 7)) << 3);
            bf16x8 k0 = *(const bf16x8*)&kc[idx * 256 + p];
            bf16x8 k1 = *(const bf16x8*)&kc[(16 + idx) * 256 + p];
            s[0] = __builtin_amdgcn_mfma_f32_16x16x32_bf16(qf[0][c], k0, s[0], 0, 0, 0);
            s[1] = __builtin_amdgcn_mfma_f32_16x16x32_bf16(qf[0][c], k1, s[1], 0, 0, 0);
            s[2] = __builtin_amdgcn_mfma_f32_16x16x32_bf16(qf[1][c], k0, s[2], 0, 0, 0);
            s[3] = __builtin_amdgcn_mfma_f32_16x16x32_bf16(qf[1][c], k1, s[3], 0, 0, 0);
        }
        __builtin_amdgcn_s_setprio(0);
        // ---- exp(ck+1) -> ps (independent of PV(ck); hides under it) ----
#pragma unroll
        for (int u = 0; u < 2; u++)
#pragma unroll
            for (int r = 0; r < 4; r++) {
                float p0 = __expf(s[u * 2][r]);
                float p1 = __expf(s[u * 2 + 1][r]);
                ls[u][r] += p0 + p1;
                pswu[u * 320 + (quad * 4 + r) * 20 + idx] =
                    (unsigned int)bf16_rtne(p0) | ((unsigned int)bf16_rtne(p1) << 16);
            }
        // ---- PV(ck) ----
        const short* vc = lds + 16384 + (ck & 1) * 8192;
        __builtin_amdgcn_s_setprio(1);
#pragma unroll
        for (int ct = 0; ct < 16; ct++) {
            bf16x8 v = *(const bf16x8*)&vc[(ct * 16 + idx) * 32 + vsw];
            oacc[0][ct] = __builtin_amdgcn_mfma_f32_16x16x32_bf16(af0, v, oacc[0][ct], 0, 0, 0);
            oacc[1][ct] = __builtin_amdgcn_mfma_f32_16x16x32_bf16(af1, v, oacc[1][ct], 0, 0, 0);
        }
        __builtin_amdgcn_s_setprio(0);
    }
    __syncthreads(); // drain V(nchunk-1)
    {
        bf16x8 af0 = *(const bf16x8*)&psw[idx * 40 + quad * 8];
        bf16x8 af1 = *(const bf16x8*)&psw[640 + idx * 40 + quad * 8];
        const short* vc = lds + 16384 + ((nchunk - 1) & 1) * 8192;
        __builtin_amdgcn_s_setprio(1);
#pragma unroll
        for (int ct = 0; ct < 16; ct++) {
            bf16x8 v = *(const bf16x8*)&vc[(ct * 16 + idx) * 32 + vsw];
            oacc[0][ct] = __builtin_amdgcn_mfma_f32_16x16x32_bf16(af0, v, oacc[0][ct], 0, 0, 0);
            oacc[1][ct] = __builtin_amdgcn_mfma_f32_16x16x32_bf16(af1, v, oacc[1][ct], 0, 0, 0);
        }
        __builtin_amdgcn_s_setprio(0);
    }
    __syncthreads(); // all compute reads of kb/vb done; reuse as epilogue scratch

    // ---- row sums ----
#pragma unroll
    for (int u = 0; u < 2; u++)
#pragma unroll
        for (int r = 0; r < 4; r++) {
            float v = ls[u][r];
            v += __shfl_xor(v, 1);
            v += __shfl_xor(v, 2);
            v += __shfl_xor(v, 4);
            v += __shfl_xor(v, 8);
            if (idx == 0)
                lpart[(size_t)slice * BS_ + b * S_ + q0 + u * 64 + wv * 16 + quad * 4 + r] = v;
        }

    // ---- O scatter: per-wave 16 KB scratch (overlays kb/vb), transposed+swz
    short* scr = lds + wv * 8192;
#pragma unroll
    for (int u = 0; u < 2; u++)
#pragma unroll
        for (int ct = 0; ct < 16; ct++) {
            int e = ct * 16 + idx;
#pragma unroll
            for (int r = 0; r < 4; r++) {
                int lr = quad * 4 + r;
                scr[u * 4096 + lr * 256 + ((((e >> 3) ^ (lr & 7)) << 3) | (e & 7))] =
                    (short)bf16_rtne(oacc[u][ct][r]);
            }
        }
    // (no barrier needed: scr is per-wave, DS in-order)

    // ---- fused out-projection: 32q x 256E (bf16) x woT -> 32q x 16o fp32 ----
    f32x4 pacc[2] = {zf, zf};
#pragma unroll
    for (int c = 0; c < 8; c++) {
        const float* ws = wo + idx * E_ + c * 32 + quad * 8;
        bf16x8 bw = pack8(*(const f32x4*)ws, *(const f32x4*)(ws + 4));
#pragma unroll
        for (int u = 0; u < 2; u++) {
            bf16x8 pa = *(const bf16x8*)&scr[u * 4096 + idx * 256 +
                                             (((c * 4 + quad) ^ (idx & 7)) << 3)];
            pacc[u] = __builtin_amdgcn_mfma_f32_16x16x32_bf16(pa, bw, pacc[u], 0, 0, 0);
        }
    }
#pragma unroll
    for (int u = 0; u < 2; u++)
#pragma unroll
        for (int r = 0; r < 4; r++) {
            int m = q0 + u * 64 + wv * 16 + quad * 4 + r;
            atomicAdd(&partial[((size_t)b * S_ + m) * NC_ + idx], pacc[u][r]);
        }
}

// ---------------------------------------------------------------------------
// norm_out: out[m][o] = partial[m][o] * (1/16)/ltot[m] + bo[o]. Grid 1024x256.
// ---------------------------------------------------------------------------
__global__ __launch_bounds__(256) void norm_out(
    const float* __restrict__ partial, const float* __restrict__ lpart,
    const float* __restrict__ bo, float* __restrict__ out) {
    int t = threadIdx.x;
    int m = blockIdx.x * 16 + (t >> 4), o = t & 15;
    float ltot = 0.f;
#pragma unroll
    for (int ns = 0; ns < NS_; ns++) ltot += lpart[(size_t)ns * BS_ + m];
    size_t i = (size_t)m * NC_ + o;
    out[i] = partial[i] * (0.0625f / ltot) + bo[o];
}

extern "C" void kernel_launch(void* const* d_in, const int* in_sizes, int n_in,
                              void* d_out, int out_size, void* d_ws, size_t ws_size,
                              hipStream_t stream) {
    const float* x  = (const float*)d_in[0];
    const float* wq = (const float*)d_in[1];
    const float* bq = (const float*)d_in[2];
    const float* wk = (const float*)d_in[3];
    const float* bk = (const float*)d_in[4];
    const float* wv = (const float*)d_in[5];
    const float* bv = (const float*)d_in[6];
    const float* wo = (const float*)d_in[7];
    const float* bo = (const float*)d_in[8];
    float* out = (float*)d_out;

    const size_t NEL = (size_t)BS_ * E_; // 4,194,304
    // ws (shorts): Qb | Kb | Vtc | partial f32 (1MB) | lpart f32 (256KB)
    short* Qb = (short*)d_ws;
    short* Kb = Qb + NEL;
    short* Vtc = Kb + NEL;
    float* partial = (float*)(Vtc + NEL);       // BS_*NC_ f32
    float* lpart = partial + (size_t)BS_ * NC_; // NS_*BS_ f32

    qkv_gemm<<<dim3(768), 256, 0, stream>>>(x, wq, wk, wv, bq, bk, bv, Qb, Kb, Vtc, partial);
    flash_attn<<<dim3(512), 256, 0, stream>>>(Qb, Kb, Vtc, wo, partial, lpart);
    norm_out<<<dim3(BS_ / 16), 256, 0, stream>>>(partial, lpart, bo, out);
}